// Round 10
// baseline (2269.284 us; speedup 1.0000x reference)
//
#include <hip/hip_runtime.h>
#include <hip/hip_bf16.h>
#include <math.h>

#define NN 50000
#define NE 400000
#define CD 128
#define EPB 32          // edges per block in edge_kernel (R10: was 64)
#define NBLK (NE / EPB) // 12500
#define HBINS 50176     // 196*256, >= NN

typedef __attribute__((ext_vector_type(8))) short bf16x8;
typedef __attribute__((ext_vector_type(4))) float f32x4;

__device__ __forceinline__ float silu_f(float z) {
    return z * __builtin_amdgcn_rcpf(1.f + __expf(-z));
}
__device__ __forceinline__ unsigned short f2bf(float x) {
    unsigned int u = __float_as_uint(x);
    u = (u + 0x7FFFu + ((u >> 16) & 1u)) >> 16;
    return (unsigned short)u;
}
__device__ __forceinline__ unsigned pk_bf16(float a, float b) {
    union { __hip_bfloat162 h2; unsigned u; } cv;
    cv.h2 = __float22bfloat162_rn(make_float2(a, b));
    return cv.u;
}

// ======================= edge sort by dst (counting sort) ===================
__global__ __launch_bounds__(256) void hist_kernel(
        const int* __restrict__ dst, int* __restrict__ hist)
{
    int e = blockIdx.x * 256 + threadIdx.x;
    if (e < NE) atomicAdd(&hist[dst[e]], 1);
}

__global__ __launch_bounds__(256) void scan1_kernel(
        const int* __restrict__ hist, int* __restrict__ offs, int* __restrict__ bsum)
{
    __shared__ int sh[256];
    const int t = threadIdx.x;
    const int i = blockIdx.x * 256 + t;
    int v = hist[i];
    sh[t] = v;
    __syncthreads();
    for (int off = 1; off < 256; off <<= 1) {
        int x = (t >= off) ? sh[t - off] : 0;
        __syncthreads();
        sh[t] += x;
        __syncthreads();
    }
    offs[i] = sh[t] - v;                 // exclusive
    if (t == 255) bsum[blockIdx.x] = sh[t];
}

__global__ __launch_bounds__(256) void scan2_kernel(int* __restrict__ bsum)
{
    __shared__ int sh[256];
    const int t = threadIdx.x;
    int v = (t < 196) ? bsum[t] : 0;
    sh[t] = v;
    __syncthreads();
    for (int off = 1; off < 256; off <<= 1) {
        int x = (t >= off) ? sh[t - off] : 0;
        __syncthreads();
        sh[t] += x;
        __syncthreads();
    }
    if (t < 196) bsum[t] = sh[t] - v;    // exclusive
}

__global__ __launch_bounds__(256) void scan3_kernel(
        const int* __restrict__ offs, const int* __restrict__ bsum,
        int* __restrict__ cursor)
{
    const int i = blockIdx.x * 256 + threadIdx.x;
    cursor[i] = offs[i] + bsum[blockIdx.x];
}

__global__ __launch_bounds__(256) void scatter_kernel(
        const int* __restrict__ eidx, const float* __restrict__ edist,
        int* __restrict__ cursor,
        int* __restrict__ ssrc, int* __restrict__ sdst, float* __restrict__ sdist)
{
    int e = blockIdx.x * 256 + threadIdx.x;
    if (e < NE) {
        int d = eidx[NE + e];
        int p = atomicAdd(&cursor[d], 1);
        ssrc[p] = eidx[e];
        sdst[p] = d;
        sdist[p] = edist[e];
    }
}

// mark boundary rows: dst of each block's first/last edge (constant over layers)
__global__ __launch_bounds__(256) void bflag_kernel(
        const int* __restrict__ sdst, unsigned char* __restrict__ bflag)
{
    int b = blockIdx.x * 256 + threadIdx.x;
    if (b < NBLK) {
        bflag[sdst[b * EPB]] = 1;
        bflag[sdst[b * EPB + EPB - 1]] = 1;
    }
}

// zero the boundary rows of the f32 side buffer (atomic targets) each layer
__global__ __launch_bounds__(128) void zside_kernel(
        const int* __restrict__ sdst, float* __restrict__ Tf32)
{
    const int b = blockIdx.x;
    const int t = threadIdx.x;
    const int r = (t < 64) ? sdst[b * EPB] : sdst[b * EPB + EPB - 1];
    *(float4*)(Tf32 + (size_t)r * 256 + (t & 63) * 4) =
        make_float4(0.f, 0.f, 0.f, 0.f);
}

// ======================= weight prep ========================================
__global__ __launch_bounds__(64) void wbig_prep(
        const float* __restrict__ We2, const float* __restrict__ Wn1,
        const float* __restrict__ Wc1, unsigned short* __restrict__ wbig)
{
    const int l = blockIdx.y;
    const int ntile = blockIdx.x / 10;
    const int ks = blockIdx.x % 10;
    const int lane = threadIdx.x;
    const int n = ntile * 16 + (lane & 15);
    const int kbase = ks * 32 + (lane >> 4) * 8;
    const float* Wn1l = Wn1 + (size_t)l * 320 * 256;
    const float* Wc1l = Wc1 + (size_t)l * 320 * 256;
    const float* We2l = We2 + (size_t)l * 64 * 64;
    const float* W1 = (n < 256) ? Wn1l : Wc1l;
    const int nn = n & 255;
    unsigned short* outp = wbig + ((((size_t)l * 32 + ntile) * 10 + ks) * 64 + lane) * 8;
    #pragma unroll
    for (int j = 0; j < 8; ++j) {
        int k = kbase + j;
        float val;
        if (k < 256) {
            val = W1[(size_t)k * 256 + nn];
        } else {
            int i = k - 256;
            float acc = 0.f;
            #pragma unroll 8
            for (int jj = 0; jj < 64; ++jj)
                acc += We2l[i * 64 + jj] * W1[(size_t)(256 + jj) * 256 + nn];
            val = acc;
        }
        outp[j] = f2bf(val);
    }
}

__global__ __launch_bounds__(64) void wn2_prep(
        const float* __restrict__ Wn2, unsigned short* __restrict__ wn2s)
{
    const int l = blockIdx.y;
    const int ntile = blockIdx.x / 8;
    const int ks = blockIdx.x % 8;
    const int lane = threadIdx.x;
    const int n = ntile * 16 + (lane & 15);
    const int kbase = ks * 32 + (lane >> 4) * 8;
    const float* Wn2l = Wn2 + (size_t)l * 256 * 128;
    unsigned short* outp = wn2s + ((((size_t)l * 8 + ntile) * 8 + ks) * 64 + lane) * 8;
    #pragma unroll
    for (int j = 0; j < 8; ++j)
        outp[j] = f2bf(Wn2l[(size_t)(kbase + j) * 128 + n]);
}

__global__ __launch_bounds__(512) void cep_prep(
        const float* __restrict__ be2,
        const float* __restrict__ Wn1, const float* __restrict__ Wc1,
        const float* __restrict__ bn1, const float* __restrict__ bc1,
        float* __restrict__ cep)
{
    const int l = blockIdx.x;
    const int j = threadIdx.x;
    const int jj = j & 255;
    const float* W1 = ((j < 256) ? Wn1 : Wc1) + (size_t)l * 320 * 256;
    const float* be2l = be2 + l * 64;
    float acc = (j < 256) ? bn1[l * 256 + jj] : bc1[l * 256 + jj];
    #pragma unroll 8
    for (int k = 0; k < 64; ++k)
        acc += be2l[k] * W1[(size_t)(256 + k) * 256 + jj];
    cep[l * 512 + j] = acc;
}

__global__ __launch_bounds__(256) void conv_kernel(
        const float* __restrict__ h, unsigned short* __restrict__ hbf)
{
    const int i = (blockIdx.x * 256 + threadIdx.x) * 4;
    float4 v = *(const float4*)(h + i);
    *(uint2*)(hbf + i) = make_uint2(pk_bf16(v.x, v.y), pk_bf16(v.z, v.w));
}

// ======================= fused edge kernel (sorted edges) ===================
// R10: EPB 64 -> 32 at the same 512 threads. Per-thread output halves to
// 32 AGPR; segsum K = 32 edges = ONE MFMA step. Register total targets
// <= 85 via __launch_bounds__(512, 6) -> 3 blocks/CU = 24 waves/CU (+50%
// TLP against the diagnosed latency wall). All verified sub-structures
// kept: manual L1 staging (R4/R5), MFMA segment-sum (R2+), interior bf16
// stores / boundary f32 atomics (R8).
// LDS ~42.5 KB -> 3 blocks/CU.
// ---------------------------------------------------------------------------
__global__ __launch_bounds__(512, 6) void edge_kernel(
        const int* __restrict__ ssrc, const int* __restrict__ sdst,
        const float* __restrict__ sdist,
        const float* __restrict__ We1l, const float* __restrict__ be1l,
        const unsigned short* __restrict__ hbf,
        const unsigned short* __restrict__ wbig_l,
        const float* __restrict__ cep_l,
        const float* __restrict__ Wc2l,
        const float* __restrict__ x_in,
        unsigned short* __restrict__ Tbf, float* __restrict__ Tf32,
        float* __restrict__ x_out)
{
    __shared__ __align__(16) unsigned short s_A[EPB][328];   // h rows + edge act
    __shared__ __align__(16) unsigned short s_tT[256][40];   // t transposed (+pad)
    __shared__ __align__(16) float s_cw[EPB][4];
    __shared__ __align__(16) unsigned short s_rid[EPB];      // run id per edge
    __shared__ int s_src[EPB], s_dst[EPB];
    __shared__ int s_rdst[EPB];                              // dst node per run
    __shared__ unsigned s_mask;

    const int tid = threadIdx.x;
    const int eb = blockIdx.x * EPB;

    {   // run structure (first wave; 32-bit mask in low lanes)
        int dv = 0;
        const bool v = (tid < EPB);
        if (v) {
            dv = sdst[eb + tid];
            s_src[tid] = ssrc[eb + tid];
            s_dst[tid] = dv;
        }
        if (tid < 64) {
            int nxt = (v && tid < EPB - 1) ? sdst[eb + tid + 1] : -1;
            unsigned mk = (unsigned)__ballot(v && dv != nxt);
            if (v) {
                int rid = __popc(mk & ((1u << tid) - 1u));
                s_rid[tid] = (unsigned short)rid;
                if (dv != nxt) s_rdst[rid] = dv;
                if (tid == 0) s_mask = mk;
            }
        }
    }
    {   // s = silu(d*We1+be1) -> s_A[e][256..319]; 16 threads/edge, 4 cols each
        const int e = tid >> 4;
        const int j0 = (tid & 15) * 4;
        const float d = sdist[eb + e];
        float a0 = silu_f(d * We1l[j0 + 0] + be1l[j0 + 0]);
        float a1 = silu_f(d * We1l[j0 + 1] + be1l[j0 + 1]);
        float a2 = silu_f(d * We1l[j0 + 2] + be1l[j0 + 2]);
        float a3 = silu_f(d * We1l[j0 + 3] + be1l[j0 + 3]);
        *(uint2*)&s_A[e][j0 + 256] = make_uint2(pk_bf16(a0, a1), pk_bf16(a2, a3));
    }
    __syncthreads();   // s_src/s_dst ready for staging

    // ---- stage h rows: 1024 chunks of 16B, 2 per thread (manual, via L1) ----
    #pragma unroll
    for (int it = 0; it < 2; ++it) {
        const int c = tid + it * 512;
        const int row = c >> 5, ch = c & 31;
        const int node = (ch < 16) ? s_src[row] : s_dst[row];
        const int koff = (ch & 15) * 8;
        bf16x8 v = *(const bf16x8*)(hbf + (size_t)node * CD + koff);
        *(bf16x8*)&s_A[row][ch * 8] = v;
    }
    __syncthreads();

    const int wave = tid >> 6, lane = tid & 63;
    const int m = lane & 15, q = lane >> 4;

    // ---- GEMM1 (acc = 4 ntiles x 2 mtiles = 32 AGPR) ----
    f32x4 acc[4][2];
    #pragma unroll
    for (int nt = 0; nt < 4; ++nt)
        #pragma unroll
        for (int mt = 0; mt < 2; ++mt)
            acc[nt][mt] = (f32x4){0.f, 0.f, 0.f, 0.f};

    if (wave < 4) {
        // node half, swapped operands: C rows = edges, cols = weight-cols
        #pragma unroll
        for (int ks = 0; ks < 10; ++ks) {
            const int koff = ks * 32 + q * 8;
            bf16x8 ef[2];
            #pragma unroll
            for (int mt = 0; mt < 2; ++mt)
                ef[mt] = *(const bf16x8*)&s_A[mt * 16 + m][koff];
            #pragma unroll
            for (int nt = 0; nt < 4; ++nt) {
                bf16x8 wf = *(const bf16x8*)(wbig_l +
                    ((size_t)((wave * 4 + nt) * 10 + ks) * 64 + lane) * 8);
                #pragma unroll
                for (int mt = 0; mt < 2; ++mt)
                    acc[nt][mt] = __builtin_amdgcn_mfma_f32_16x16x32_bf16(
                        ef[mt], wf, acc[nt][mt], 0, 0, 0);
            }
        }
    } else {
        // coord half, original orientation: C cols = edges
        #pragma unroll
        for (int ks = 0; ks < 10; ++ks) {
            const int koff = ks * 32 + q * 8;
            bf16x8 ef[2];
            #pragma unroll
            for (int mt = 0; mt < 2; ++mt)
                ef[mt] = *(const bf16x8*)&s_A[mt * 16 + m][koff];
            #pragma unroll
            for (int nt = 0; nt < 4; ++nt) {
                bf16x8 wf = *(const bf16x8*)(wbig_l +
                    ((size_t)((wave * 4 + nt) * 10 + ks) * 64 + lane) * 8);
                #pragma unroll
                for (int mt = 0; mt < 2; ++mt)
                    acc[nt][mt] = __builtin_amdgcn_mfma_f32_16x16x32_bf16(
                        wf, ef[mt], acc[nt][mt], 0, 0, 0);
            }
        }
    }

    // ---- epilogue ----
    if (wave < 4) {
        // t -> transposed LDS: lane holds 4 consecutive edges per (nt,mt)
        #pragma unroll
        for (int nt = 0; nt < 4; ++nt) {
            const int col = (wave * 4 + nt) * 16 + m;
            const float ce = cep_l[col];
            #pragma unroll
            for (int mt = 0; mt < 2; ++mt) {
                float t0 = silu_f(acc[nt][mt][0] + ce);
                float t1 = silu_f(acc[nt][mt][1] + ce);
                float t2 = silu_f(acc[nt][mt][2] + ce);
                float t3 = silu_f(acc[nt][mt][3] + ce);
                *(uint2*)&s_tT[col][(mt * 16 + q * 4) ^ ((m & 3) << 3)] =
                    make_uint2(pk_bf16(t0, t1), pk_bf16(t2, t3));
            }
        }
    } else {
        // coord half: in-register partial dot silu(pre)*Wc2
        float p[2] = {0.f, 0.f};
        #pragma unroll
        for (int nt = 0; nt < 4; ++nt) {
            const int c0 = (wave * 4 + nt) * 16 + q * 4;   // 256..511
            const float4 ce = *(const float4*)&cep_l[c0];
            const float4 wv = *(const float4*)&Wc2l[c0 - 256];
            #pragma unroll
            for (int mt = 0; mt < 2; ++mt) {
                p[mt] += silu_f(acc[nt][mt][0] + ce.x) * wv.x;
                p[mt] += silu_f(acc[nt][mt][1] + ce.y) * wv.y;
                p[mt] += silu_f(acc[nt][mt][2] + ce.z) * wv.z;
                p[mt] += silu_f(acc[nt][mt][3] + ce.w) * wv.w;
            }
        }
        #pragma unroll
        for (int mt = 0; mt < 2; ++mt) {
            p[mt] += __shfl_xor(p[mt], 16);
            p[mt] += __shfl_xor(p[mt], 32);
        }
        if (lane < 16) {
            #pragma unroll
            for (int mt = 0; mt < 2; ++mt)
                s_cw[mt * 16 + lane][wave - 4] = p[mt];
        }
    }
    __syncthreads();   // s_tT / s_cw ready

    // ---- MFMA segment-sum, all 8 waves, single K step (32 edges) ----
    {
        const unsigned mask = s_mask;
        const int nruns = __popc(mask);
        f32x4 a2[2][2];   // [mt2 = col tile][nt = run tile]
        bf16x8 af[2];
        #pragma unroll
        for (int mt2 = 0; mt2 < 2; ++mt2)
            af[mt2] = *(const bf16x8*)&s_tT[(wave * 2 + mt2) * 16 + m]
                                       [(q * 8) ^ ((m & 3) << 3)];
        const unsigned* rp = (const unsigned*)&s_rid[q * 8];
        const unsigned r01 = rp[0], r23 = rp[1], r45 = rp[2], r67 = rp[3];
        #pragma unroll
        for (int nt = 0; nt < 2; ++nt) {
            const unsigned n = (unsigned)(nt * 16 + m);
            unsigned gw[4];
            gw[0] = ((r01 & 0xFFFFu) == n ? 0x3F80u : 0u) |
                    ((r01 >> 16)      == n ? 0x3F800000u : 0u);
            gw[1] = ((r23 & 0xFFFFu) == n ? 0x3F80u : 0u) |
                    ((r23 >> 16)      == n ? 0x3F800000u : 0u);
            gw[2] = ((r45 & 0xFFFFu) == n ? 0x3F80u : 0u) |
                    ((r45 >> 16)      == n ? 0x3F800000u : 0u);
            gw[3] = ((r67 & 0xFFFFu) == n ? 0x3F80u : 0u) |
                    ((r67 >> 16)      == n ? 0x3F800000u : 0u);
            const bf16x8 bfr = *(const bf16x8*)gw;
            #pragma unroll
            for (int mt2 = 0; mt2 < 2; ++mt2)
                a2[mt2][nt] = __builtin_amdgcn_mfma_f32_16x16x32_bf16(
                    af[mt2], bfr,
                    (f32x4){0.f, 0.f, 0.f, 0.f}, 0, 0, 0);
        }
        // Interior runs own their row exclusively (dst-sorted edges) ->
        // bf16-packed 8B stores into Tbf. Boundary runs (first/last of
        // block; flagged for node) -> f32 atomics into Tf32.
        #pragma unroll
        for (int nt = 0; nt < 2; ++nt) {
            const int r = nt * 16 + m;
            if (r < nruns) {
                const bool bdry = (r == 0) || (r == nruns - 1);
                if (bdry) {
                    float* bp = Tf32 + (size_t)s_rdst[r] * 256;
                    #pragma unroll
                    for (int mt2 = 0; mt2 < 2; ++mt2) {
                        const int c = (wave * 2 + mt2) * 16 + q * 4;
                        atomicAdd(&bp[c],     a2[mt2][nt][0]);
                        atomicAdd(&bp[c + 1], a2[mt2][nt][1]);
                        atomicAdd(&bp[c + 2], a2[mt2][nt][2]);
                        atomicAdd(&bp[c + 3], a2[mt2][nt][3]);
                    }
                } else {
                    unsigned short* bp = Tbf + (size_t)s_rdst[r] * 256;
                    #pragma unroll
                    for (int mt2 = 0; mt2 < 2; ++mt2) {
                        const int c = (wave * 2 + mt2) * 16 + q * 4;
                        *(uint2*)&bp[c] = make_uint2(
                            pk_bf16(a2[mt2][nt][0], a2[mt2][nt][1]),
                            pk_bf16(a2[mt2][nt][2], a2[mt2][nt][3]));
                    }
                }
            }
        }
    }
    if (wave == 2 && lane < EPB) {
        // finalize coord weights, scatter x
        const int e = lane;
        float4 pv = *(const float4*)&s_cw[e][0];
        float cw = pv.x + pv.y + pv.z + pv.w;
        int sn = s_src[e], dn = s_dst[e];
        float dx0 = x_in[sn * 3 + 0] - x_in[dn * 3 + 0];
        float dx1 = x_in[sn * 3 + 1] - x_in[dn * 3 + 1];
        float dx2 = x_in[sn * 3 + 2] - x_in[dn * 3 + 2];
        atomicAdd(&x_out[dn * 3 + 0], cw * dx0);
        atomicAdd(&x_out[dn * 3 + 1], cw * dx1);
        atomicAdd(&x_out[dn * 3 + 2], cw * dx2);
    }
}

// ======================= node kernel: h += T@Wn2 + deg*bn2 ==================
__global__ __launch_bounds__(256) void node_kernel(
        const unsigned short* __restrict__ Tbf, const float* __restrict__ Tf32,
        const unsigned char* __restrict__ bflag, const int* __restrict__ deg,
        const unsigned short* __restrict__ wn2_l, const float* __restrict__ bn2l,
        float* __restrict__ h, unsigned short* __restrict__ hbf)
{
    const int nb = blockIdx.x * 64;
    const int tid = threadIdx.x;
    const int wave = tid >> 6, lane = tid & 63;
    const int m = lane & 15, q = lane >> 4;

    int fl[4];
    #pragma unroll
    for (int mt = 0; mt < 4; ++mt) {
        const int node = nb + mt * 16 + m;
        fl[mt] = (node < NN) ? (int)bflag[node] : 0;
    }

    f32x4 acc[2][4];
    #pragma unroll
    for (int nt = 0; nt < 2; ++nt)
        #pragma unroll
        for (int mt = 0; mt < 4; ++mt)
            acc[nt][mt] = (f32x4){0.f, 0.f, 0.f, 0.f};

    #pragma unroll
    for (int ks = 0; ks < 8; ++ks) {
        bf16x8 af[4];
        #pragma unroll
        for (int mt = 0; mt < 4; ++mt) {
            const int node = nb + mt * 16 + m;
            if (node < NN) {
                if (!fl[mt]) {
                    af[mt] = *(const bf16x8*)(Tbf + (size_t)node * 256 + ks * 32 + q * 8);
                } else {
                    const float* tp = Tf32 + (size_t)node * 256 + ks * 32 + q * 8;
                    float4 f0 = *(const float4*)tp;
                    float4 f1 = *(const float4*)(tp + 4);
                    unsigned u[4] = { pk_bf16(f0.x, f0.y), pk_bf16(f0.z, f0.w),
                                      pk_bf16(f1.x, f1.y), pk_bf16(f1.z, f1.w) };
                    af[mt] = *(const bf16x8*)u;
                }
            } else {
                af[mt] = (bf16x8){0,0,0,0,0,0,0,0};
            }
        }
        #pragma unroll
        for (int nt = 0; nt < 2; ++nt) {
            bf16x8 wf = *(const bf16x8*)(wn2_l +
                ((size_t)((wave * 2 + nt) * 8 + ks) * 64 + lane) * 8);
            #pragma unroll
            for (int mt = 0; mt < 4; ++mt)
                acc[nt][mt] = __builtin_amdgcn_mfma_f32_16x16x32_bf16(af[mt], wf, acc[nt][mt], 0, 0, 0);
        }
    }
    #pragma unroll
    for (int nt = 0; nt < 2; ++nt) {
        const int col = (wave * 2 + nt) * 16 + m;
        const float bb = bn2l[col];
        #pragma unroll
        for (int mt = 0; mt < 4; ++mt) {
            #pragma unroll
            for (int i = 0; i < 4; ++i) {
                const int node = nb + mt * 16 + q * 4 + i;
                if (node < NN) {
                    float val = acc[nt][mt][i] + (float)deg[node] * bb
                              + h[(size_t)node * CD + col];
                    h[(size_t)node * CD + col] = val;
                    hbf[(size_t)node * CD + col] = f2bf(val);
                }
            }
        }
    }
}

// ======================= final layernorm ====================================
__global__ __launch_bounds__(256) void final_kernel(
        const float* __restrict__ h, const float* __restrict__ x,
        const float* __restrict__ gamma, const float* __restrict__ beta,
        float* __restrict__ out)
{
    const int lane = threadIdx.x & 63;
    const int wave = threadIdx.x >> 6;
    const int n = blockIdx.x * 4 + wave;
    float v0 = h[(size_t)n * CD + lane];
    float v1 = h[(size_t)n * CD + 64 + lane];
    float ssum = v0 + v1;
    for (int off = 32; off; off >>= 1) ssum += __shfl_xor(ssum, off);
    float mu = ssum * (1.f / 128.f);
    float d0 = v0 - mu, d1 = v1 - mu;
    float sq = d0 * d0 + d1 * d1;
    for (int off = 32; off; off >>= 1) sq += __shfl_xor(sq, off);
    float rstd = rsqrtf(sq * (1.f / 128.f) + 1e-5f);
    out[(size_t)n * CD + lane]      = gamma[lane]      * d0 * rstd + beta[lane];
    out[(size_t)n * CD + 64 + lane] = gamma[64 + lane] * d1 * rstd + beta[64 + lane];
    if (threadIdx.x < 12) {
        int nn = blockIdx.x * 4 + threadIdx.x / 3;
        int c = threadIdx.x % 3;
        out[(size_t)NN * CD + nn * 3 + c] = x[nn * 3 + c];
    }
}

static inline size_t align_up(size_t v) { return (v + 255) & ~(size_t)255; }

extern "C" void kernel_launch(void* const* d_in, const int* in_sizes, int n_in,
                              void* d_out, int out_size, void* d_ws, size_t ws_size,
                              hipStream_t stream)
{
    const float* single = (const float*)d_in[0];
    const float* coords = (const float*)d_in[2];
    const int*   eidx   = (const int*)d_in[3];
    const float* edist  = (const float*)d_in[4];
    const float* We1 = (const float*)d_in[5];
    const float* be1 = (const float*)d_in[6];
    const float* We2 = (const float*)d_in[7];
    const float* be2 = (const float*)d_in[8];
    const float* Wn1 = (const float*)d_in[9];
    const float* bn1 = (const float*)d_in[10];
    const float* Wn2 = (const float*)d_in[11];
    const float* bn2 = (const float*)d_in[12];
    const float* Wc1 = (const float*)d_in[13];
    const float* bc1 = (const float*)d_in[14];
    const float* Wc2 = (const float*)d_in[15];
    const float* gamma = (const float*)d_in[16];
    const float* beta  = (const float*)d_in[17];
    float* out = (float*)d_out;

    char* w = (char*)d_ws;
    float* h0  = (float*)w;  w += align_up((size_t)NN * CD * 4);
    float* x0  = (float*)w;  w += align_up((size_t)NN * 3 * 4);
    float* x1  = (float*)w;  w += align_up((size_t)NN * 3 * 4);
    unsigned short* hbf  = (unsigned short*)w; w += align_up((size_t)NN * CD * 2);
    unsigned short* wbig = (unsigned short*)w; w += align_up((size_t)4 * 512 * 320 * 2);
    unsigned short* wn2s = (unsigned short*)w; w += align_up((size_t)4 * 256 * 128 * 2);
    float* cep = (float*)w;  w += align_up((size_t)4 * 512 * 4);
    int* hist   = (int*)w;   w += align_up((size_t)HBINS * 4);
    int* offs   = (int*)w;   w += align_up((size_t)HBINS * 4);
    int* cursor = (int*)w;   w += align_up((size_t)HBINS * 4);
    int* bsum   = (int*)w;   w += align_up((size_t)256 * 4);
    int* ssrc   = (int*)w;   w += align_up((size_t)NE * 4);
    int* sdst   = (int*)w;   w += align_up((size_t)NE * 4);
    float* sdist = (float*)w; w += align_up((size_t)NE * 4);
    unsigned char* bflag = (unsigned char*)w; w += align_up((size_t)NN);
    unsigned short* Tbf = (unsigned short*)w; w += align_up((size_t)NN * 256 * 2);
    float* Tf32 = (float*)w; w += align_up((size_t)NN * 256 * 4);

    // ---- sort edges by dst (once; constant across layers) ----
    hipMemsetAsync(hist, 0, (size_t)HBINS * 4, stream);
    hist_kernel<<<(NE + 255) / 256, 256, 0, stream>>>(eidx + NE, hist);
    scan1_kernel<<<HBINS / 256, 256, 0, stream>>>(hist, offs, bsum);
    scan2_kernel<<<1, 256, 0, stream>>>(bsum);
    scan3_kernel<<<HBINS / 256, 256, 0, stream>>>(offs, bsum, cursor);
    scatter_kernel<<<(NE + 255) / 256, 256, 0, stream>>>(eidx, edist, cursor, ssrc, sdst, sdist);
    hipMemsetAsync(bflag, 0, (size_t)NN, stream);
    bflag_kernel<<<(NBLK + 255) / 256, 256, 0, stream>>>(sdst, bflag);

    // ---- weight prep ----
    wbig_prep<<<dim3(320, 4), 64, 0, stream>>>(We2, Wn1, Wc1, wbig);
    wn2_prep<<<dim3(64, 4), 64, 0, stream>>>(Wn2, wn2s);
    cep_prep<<<4, 512, 0, stream>>>(be2, Wn1, Wc1, bn1, bc1, cep);

    hipMemcpyAsync(h0, single, (size_t)NN * CD * 4, hipMemcpyDeviceToDevice, stream);
    hipMemcpyAsync(x0, coords, (size_t)NN * 3 * 4, hipMemcpyDeviceToDevice, stream);
    conv_kernel<<<(NN * CD) / 1024, 256, 0, stream>>>(single, hbf);

    // Tbf zeroed ONCE: interior rows are fully rewritten every layer,
    // boundary rows are read from Tf32 (bflag), deg-0 rows stay zero.
    hipMemsetAsync(Tbf, 0, (size_t)NN * 256 * 2, stream);

    float* xc = x0; float* xn = x1;
    for (int l = 0; l < 4; ++l) {
        zside_kernel<<<NBLK, 128, 0, stream>>>(sdst, Tf32);     // boundary rows
        hipMemcpyAsync(xn, xc, (size_t)NN * 3 * 4, hipMemcpyDeviceToDevice, stream);
        edge_kernel<<<NBLK, 512, 0, stream>>>(
            ssrc, sdst, sdist,
            We1 + l * 64, be1 + l * 64,
            hbf,
            wbig + (size_t)l * 512 * 320,
            cep + l * 512,
            Wc2 + l * 256,
            xc, Tbf, Tf32, xn);
        node_kernel<<<(NN + 63) / 64, 256, 0, stream>>>(
            Tbf, Tf32, bflag, hist,
            wn2s + (size_t)l * 256 * 128,
            bn2 + l * CD, h0, hbf);
        float* t = xc; xc = xn; xn = t;
    }
    final_kernel<<<NN / 4, 256, 0, stream>>>(h0, xc, gamma, beta, out);
}

// Round 12
// 1325.094 us; speedup vs baseline: 1.7125x; 1.7125x over previous
//
#include <hip/hip_runtime.h>
#include <hip/hip_bf16.h>
#include <math.h>

#define NN 50000
#define NE 400000
#define CD 128
#define EPB 64          // edges per block in edge_kernel
#define NBLK (NE / EPB) // 6250
#define HBINS 50176     // 196*256, >= NN

typedef __attribute__((ext_vector_type(8))) short bf16x8;
typedef __attribute__((ext_vector_type(4))) float f32x4;

__device__ __forceinline__ float silu_f(float z) {
    return z * __builtin_amdgcn_rcpf(1.f + __expf(-z));
}
__device__ __forceinline__ unsigned short f2bf(float x) {
    unsigned int u = __float_as_uint(x);
    u = (u + 0x7FFFu + ((u >> 16) & 1u)) >> 16;
    return (unsigned short)u;
}
__device__ __forceinline__ unsigned pk_bf16(float a, float b) {
    union { __hip_bfloat162 h2; unsigned u; } cv;
    cv.h2 = __float22bfloat162_rn(make_float2(a, b));
    return cv.u;
}

// ======================= edge sort by dst (counting sort) ===================
__global__ __launch_bounds__(256) void hist_kernel(
        const int* __restrict__ dst, int* __restrict__ hist)
{
    int e = blockIdx.x * 256 + threadIdx.x;
    if (e < NE) atomicAdd(&hist[dst[e]], 1);
}

__global__ __launch_bounds__(256) void scan1_kernel(
        const int* __restrict__ hist, int* __restrict__ offs, int* __restrict__ bsum)
{
    __shared__ int sh[256];
    const int t = threadIdx.x;
    const int i = blockIdx.x * 256 + t;
    int v = hist[i];
    sh[t] = v;
    __syncthreads();
    for (int off = 1; off < 256; off <<= 1) {
        int x = (t >= off) ? sh[t - off] : 0;
        __syncthreads();
        sh[t] += x;
        __syncthreads();
    }
    offs[i] = sh[t] - v;                 // exclusive
    if (t == 255) bsum[blockIdx.x] = sh[t];
}

__global__ __launch_bounds__(256) void scan2_kernel(int* __restrict__ bsum)
{
    __shared__ int sh[256];
    const int t = threadIdx.x;
    int v = (t < 196) ? bsum[t] : 0;
    sh[t] = v;
    __syncthreads();
    for (int off = 1; off < 256; off <<= 1) {
        int x = (t >= off) ? sh[t - off] : 0;
        __syncthreads();
        sh[t] += x;
        __syncthreads();
    }
    if (t < 196) bsum[t] = sh[t] - v;    // exclusive
}

__global__ __launch_bounds__(256) void scan3_kernel(
        const int* __restrict__ offs, const int* __restrict__ bsum,
        int* __restrict__ cursor)
{
    const int i = blockIdx.x * 256 + threadIdx.x;
    cursor[i] = offs[i] + bsum[blockIdx.x];
}

__global__ __launch_bounds__(256) void scatter_kernel(
        const int* __restrict__ eidx, const float* __restrict__ edist,
        int* __restrict__ cursor,
        int* __restrict__ ssrc, int* __restrict__ sdst, float* __restrict__ sdist)
{
    int e = blockIdx.x * 256 + threadIdx.x;
    if (e < NE) {
        int d = eidx[NE + e];
        int p = atomicAdd(&cursor[d], 1);
        ssrc[p] = eidx[e];
        sdst[p] = d;
        sdist[p] = edist[e];
    }
}

// mark boundary rows: dst of each block's first/last edge (constant over layers)
__global__ __launch_bounds__(256) void bflag_kernel(
        const int* __restrict__ sdst, unsigned char* __restrict__ bflag)
{
    int b = blockIdx.x * 256 + threadIdx.x;
    if (b < NBLK) {
        bflag[sdst[b * EPB]] = 1;
        bflag[sdst[b * EPB + EPB - 1]] = 1;
    }
}

// zero the boundary rows of the f32 side buffer (atomic targets) each layer
__global__ __launch_bounds__(128) void zside_kernel(
        const int* __restrict__ sdst, float* __restrict__ Tf32)
{
    const int b = blockIdx.x;
    const int t = threadIdx.x;
    const int r = (t < 64) ? sdst[b * EPB] : sdst[b * EPB + EPB - 1];
    *(float4*)(Tf32 + (size_t)r * 256 + (t & 63) * 4) =
        make_float4(0.f, 0.f, 0.f, 0.f);
}

// ======================= weight prep ========================================
__global__ __launch_bounds__(64) void wbig_prep(
        const float* __restrict__ We2, const float* __restrict__ Wn1,
        const float* __restrict__ Wc1, unsigned short* __restrict__ wbig)
{
    const int l = blockIdx.y;
    const int ntile = blockIdx.x / 10;
    const int ks = blockIdx.x % 10;
    const int lane = threadIdx.x;
    const int n = ntile * 16 + (lane & 15);
    const int kbase = ks * 32 + (lane >> 4) * 8;
    const float* Wn1l = Wn1 + (size_t)l * 320 * 256;
    const float* Wc1l = Wc1 + (size_t)l * 320 * 256;
    const float* We2l = We2 + (size_t)l * 64 * 64;
    const float* W1 = (n < 256) ? Wn1l : Wc1l;
    const int nn = n & 255;
    unsigned short* outp = wbig + ((((size_t)l * 32 + ntile) * 10 + ks) * 64 + lane) * 8;
    #pragma unroll
    for (int j = 0; j < 8; ++j) {
        int k = kbase + j;
        float val;
        if (k < 256) {
            val = W1[(size_t)k * 256 + nn];
        } else {
            int i = k - 256;
            float acc = 0.f;
            #pragma unroll 8
            for (int jj = 0; jj < 64; ++jj)
                acc += We2l[i * 64 + jj] * W1[(size_t)(256 + jj) * 256 + nn];
            val = acc;
        }
        outp[j] = f2bf(val);
    }
}

__global__ __launch_bounds__(64) void wn2_prep(
        const float* __restrict__ Wn2, unsigned short* __restrict__ wn2s)
{
    const int l = blockIdx.y;
    const int ntile = blockIdx.x / 8;
    const int ks = blockIdx.x % 8;
    const int lane = threadIdx.x;
    const int n = ntile * 16 + (lane & 15);
    const int kbase = ks * 32 + (lane >> 4) * 8;
    const float* Wn2l = Wn2 + (size_t)l * 256 * 128;
    unsigned short* outp = wn2s + ((((size_t)l * 8 + ntile) * 8 + ks) * 64 + lane) * 8;
    #pragma unroll
    for (int j = 0; j < 8; ++j)
        outp[j] = f2bf(Wn2l[(size_t)(kbase + j) * 128 + n]);
}

__global__ __launch_bounds__(512) void cep_prep(
        const float* __restrict__ be2,
        const float* __restrict__ Wn1, const float* __restrict__ Wc1,
        const float* __restrict__ bn1, const float* __restrict__ bc1,
        float* __restrict__ cep)
{
    const int l = blockIdx.x;
    const int j = threadIdx.x;
    const int jj = j & 255;
    const float* W1 = ((j < 256) ? Wn1 : Wc1) + (size_t)l * 320 * 256;
    const float* be2l = be2 + l * 64;
    float acc = (j < 256) ? bn1[l * 256 + jj] : bc1[l * 256 + jj];
    #pragma unroll 8
    for (int k = 0; k < 64; ++k)
        acc += be2l[k] * W1[(size_t)(256 + k) * 256 + jj];
    cep[l * 512 + j] = acc;
}

__global__ __launch_bounds__(256) void conv_kernel(
        const float* __restrict__ h, unsigned short* __restrict__ hbf)
{
    const int i = (blockIdx.x * 256 + threadIdx.x) * 4;
    float4 v = *(const float4*)(h + i);
    *(uint2*)(hbf + i) = make_uint2(pk_bf16(v.x, v.y), pk_bf16(v.z, v.w));
}

// ======================= fused edge kernel (sorted edges) ===================
// R8-EXACT (verified 1356 us best): manual VGPR-round-trip staging (L1 path
// load-bearing, R4/R5), 16x16 GEMM at the full 64 VGPR + 64 AGPR budget
// (R9/R10: any restructure to free registers spills to scratch), MFMA
// segment-sum, interior bf16 stores / boundary f32 atomics (R8).
// LDS ~80.8 KB -> 2 blocks/CU (16 waves; register-pinned cap).
// ---------------------------------------------------------------------------
__global__ __launch_bounds__(512, 4) void edge_kernel(
        const int* __restrict__ ssrc, const int* __restrict__ sdst,
        const float* __restrict__ sdist,
        const float* __restrict__ We1l, const float* __restrict__ be1l,
        const unsigned short* __restrict__ hbf,
        const unsigned short* __restrict__ wbig_l,
        const float* __restrict__ cep_l,
        const float* __restrict__ Wc2l,
        const float* __restrict__ x_in,
        unsigned short* __restrict__ Tbf, float* __restrict__ Tf32,
        float* __restrict__ x_out)
{
    __shared__ __align__(16) unsigned short s_A[EPB][328];   // h rows + edge act
    __shared__ __align__(16) unsigned short s_tT[256][72];   // t transposed (+pad)
    __shared__ __align__(16) float s_cw[EPB][4];
    __shared__ __align__(16) unsigned short s_rid[EPB];      // run id per edge
    __shared__ int s_src[EPB], s_dst[EPB];
    __shared__ int s_rdst[EPB];                              // dst node per run
    __shared__ unsigned long long s_mask;

    const int tid = threadIdx.x;
    const int eb = blockIdx.x * EPB;

    if (tid < EPB) {
        int dv = sdst[eb + tid];
        s_src[tid] = ssrc[eb + tid];
        s_dst[tid] = dv;
        int nxt = (tid == EPB - 1) ? -1 : sdst[eb + tid + 1];
        unsigned long long mk = __ballot(dv != nxt);
        int rid = __popcll(mk & ((1ull << tid) - 1ull));
        s_rid[tid] = (unsigned short)rid;
        if (dv != nxt) s_rdst[rid] = dv;
        if (tid == 0) s_mask = mk;
    }
    {   // s = silu(d*We1+be1) -> s_A[e][256..319]; 8 threads/edge, 8 cols each
        const int e = tid >> 3;
        const int j0 = (tid & 7) * 8;
        const float d = sdist[eb + e];
        unsigned tmp[4];
        #pragma unroll
        for (int j = 0; j < 4; ++j) {
            float a = silu_f(d * We1l[j0 + 2 * j] + be1l[j0 + 2 * j]);
            float b = silu_f(d * We1l[j0 + 2 * j + 1] + be1l[j0 + 2 * j + 1]);
            tmp[j] = pk_bf16(a, b);
        }
        *(bf16x8*)&s_A[e][j0 + 256] = *(const bf16x8*)tmp;
    }
    __syncthreads();   // s_src/s_dst ready for staging

    // ---- stage h rows: 2048 chunks of 16B, 4 per thread (manual, via L1) ----
    #pragma unroll
    for (int it = 0; it < 4; ++it) {
        const int c = tid + it * 512;
        const int row = c >> 5, ch = c & 31;
        const int node = (ch < 16) ? s_src[row] : s_dst[row];
        const int koff = (ch & 15) * 8;
        bf16x8 v = *(const bf16x8*)(hbf + (size_t)node * CD + koff);
        *(bf16x8*)&s_A[row][ch * 8] = v;
    }
    __syncthreads();

    const int wave = tid >> 6, lane = tid & 63;
    const int m = lane & 15, q = lane >> 4;

    // ---- GEMM1 ----
    f32x4 acc[4][4];   // [nt][mt]
    #pragma unroll
    for (int nt = 0; nt < 4; ++nt)
        #pragma unroll
        for (int mt = 0; mt < 4; ++mt)
            acc[nt][mt] = (f32x4){0.f, 0.f, 0.f, 0.f};

    if (wave < 4) {
        // node half, swapped operands: C rows = edges, cols = weight-cols
        #pragma unroll
        for (int ks = 0; ks < 10; ++ks) {
            const int koff = ks * 32 + q * 8;
            bf16x8 ef[4];
            #pragma unroll
            for (int mt = 0; mt < 4; ++mt)
                ef[mt] = *(const bf16x8*)&s_A[mt * 16 + m][koff];
            #pragma unroll
            for (int nt = 0; nt < 4; ++nt) {
                bf16x8 wf = *(const bf16x8*)(wbig_l +
                    ((size_t)((wave * 4 + nt) * 10 + ks) * 64 + lane) * 8);
                #pragma unroll
                for (int mt = 0; mt < 4; ++mt)
                    acc[nt][mt] = __builtin_amdgcn_mfma_f32_16x16x32_bf16(
                        ef[mt], wf, acc[nt][mt], 0, 0, 0);
            }
        }
    } else {
        // coord half, original orientation: C cols = edges
        #pragma unroll
        for (int ks = 0; ks < 10; ++ks) {
            const int koff = ks * 32 + q * 8;
            bf16x8 ef[4];
            #pragma unroll
            for (int mt = 0; mt < 4; ++mt)
                ef[mt] = *(const bf16x8*)&s_A[mt * 16 + m][koff];
            #pragma unroll
            for (int nt = 0; nt < 4; ++nt) {
                bf16x8 wf = *(const bf16x8*)(wbig_l +
                    ((size_t)((wave * 4 + nt) * 10 + ks) * 64 + lane) * 8);
                #pragma unroll
                for (int mt = 0; mt < 4; ++mt)
                    acc[nt][mt] = __builtin_amdgcn_mfma_f32_16x16x32_bf16(
                        wf, ef[mt], acc[nt][mt], 0, 0, 0);
            }
        }
    }

    // ---- epilogue ----
    if (wave < 4) {
        // t -> transposed LDS: lane holds 4 consecutive edges per (nt,mt)
        #pragma unroll
        for (int nt = 0; nt < 4; ++nt) {
            const int col = (wave * 4 + nt) * 16 + m;
            const float ce = cep_l[col];
            #pragma unroll
            for (int mt = 0; mt < 4; ++mt) {
                float t0 = silu_f(acc[nt][mt][0] + ce);
                float t1 = silu_f(acc[nt][mt][1] + ce);
                float t2 = silu_f(acc[nt][mt][2] + ce);
                float t3 = silu_f(acc[nt][mt][3] + ce);
                *(uint2*)&s_tT[col][(mt * 16 + q * 4) ^ ((m & 3) << 3)] =
                    make_uint2(pk_bf16(t0, t1), pk_bf16(t2, t3));
            }
        }
    } else {
        // coord half: in-register partial dot silu(pre)*Wc2
        float p[4] = {0.f, 0.f, 0.f, 0.f};
        #pragma unroll
        for (int nt = 0; nt < 4; ++nt) {
            const int c0 = (wave * 4 + nt) * 16 + q * 4;   // 256..511
            const float4 ce = *(const float4*)&cep_l[c0];
            const float4 wv = *(const float4*)&Wc2l[c0 - 256];
            #pragma unroll
            for (int mt = 0; mt < 4; ++mt) {
                p[mt] += silu_f(acc[nt][mt][0] + ce.x) * wv.x;
                p[mt] += silu_f(acc[nt][mt][1] + ce.y) * wv.y;
                p[mt] += silu_f(acc[nt][mt][2] + ce.z) * wv.z;
                p[mt] += silu_f(acc[nt][mt][3] + ce.w) * wv.w;
            }
        }
        #pragma unroll
        for (int mt = 0; mt < 4; ++mt) {
            p[mt] += __shfl_xor(p[mt], 16);
            p[mt] += __shfl_xor(p[mt], 32);
        }
        if (lane < 16) {
            #pragma unroll
            for (int mt = 0; mt < 4; ++mt)
                s_cw[mt * 16 + lane][wave - 4] = p[mt];
        }
    }
    __syncthreads();   // s_tT / s_cw ready

    // ---- MFMA segment-sum on all 8 waves: out^T[c][r] = sum_e tT[c][e]G[e][r]
    {
        const unsigned long long mask = s_mask;
        const int nruns = __popcll(mask);
        f32x4 a2[2][4];   // [mt2 = col tile][nt = run tile]
        #pragma unroll
        for (int mt2 = 0; mt2 < 2; ++mt2)
            #pragma unroll
            for (int nt = 0; nt < 4; ++nt)
                a2[mt2][nt] = (f32x4){0.f, 0.f, 0.f, 0.f};
        #pragma unroll
        for (int ks = 0; ks < 2; ++ks) {
            bf16x8 af[2];
            #pragma unroll
            for (int mt2 = 0; mt2 < 2; ++mt2)
                af[mt2] = *(const bf16x8*)&s_tT[(wave * 2 + mt2) * 16 + m]
                                           [(ks * 32 + q * 8) ^ ((m & 3) << 3)];
            const unsigned* rp = (const unsigned*)&s_rid[ks * 32 + q * 8];
            const unsigned r01 = rp[0], r23 = rp[1], r45 = rp[2], r67 = rp[3];
            #pragma unroll
            for (int nt = 0; nt < 4; ++nt) {
                const unsigned n = (unsigned)(nt * 16 + m);
                unsigned gw[4];
                gw[0] = ((r01 & 0xFFFFu) == n ? 0x3F80u : 0u) |
                        ((r01 >> 16)      == n ? 0x3F800000u : 0u);
                gw[1] = ((r23 & 0xFFFFu) == n ? 0x3F80u : 0u) |
                        ((r23 >> 16)      == n ? 0x3F800000u : 0u);
                gw[2] = ((r45 & 0xFFFFu) == n ? 0x3F80u : 0u) |
                        ((r45 >> 16)      == n ? 0x3F800000u : 0u);
                gw[3] = ((r67 & 0xFFFFu) == n ? 0x3F80u : 0u) |
                        ((r67 >> 16)      == n ? 0x3F800000u : 0u);
                const bf16x8 bfr = *(const bf16x8*)gw;
                #pragma unroll
                for (int mt2 = 0; mt2 < 2; ++mt2)
                    a2[mt2][nt] = __builtin_amdgcn_mfma_f32_16x16x32_bf16(
                        af[mt2], bfr, a2[mt2][nt], 0, 0, 0);
            }
        }
        // Interior runs own their row exclusively (dst-sorted edges) ->
        // bf16-packed 8B stores into Tbf. Boundary runs (first/last of
        // block; flagged for node) -> f32 atomics into Tf32.
        #pragma unroll
        for (int nt = 0; nt < 4; ++nt) {
            const int r = nt * 16 + m;
            if (r < nruns) {
                const bool bdry = (r == 0) || (r == nruns - 1);
                if (bdry) {
                    float* bp = Tf32 + (size_t)s_rdst[r] * 256;
                    #pragma unroll
                    for (int mt2 = 0; mt2 < 2; ++mt2) {
                        const int c = (wave * 2 + mt2) * 16 + q * 4;
                        atomicAdd(&bp[c],     a2[mt2][nt][0]);
                        atomicAdd(&bp[c + 1], a2[mt2][nt][1]);
                        atomicAdd(&bp[c + 2], a2[mt2][nt][2]);
                        atomicAdd(&bp[c + 3], a2[mt2][nt][3]);
                    }
                } else {
                    unsigned short* bp = Tbf + (size_t)s_rdst[r] * 256;
                    #pragma unroll
                    for (int mt2 = 0; mt2 < 2; ++mt2) {
                        const int c = (wave * 2 + mt2) * 16 + q * 4;
                        *(uint2*)&bp[c] = make_uint2(
                            pk_bf16(a2[mt2][nt][0], a2[mt2][nt][1]),
                            pk_bf16(a2[mt2][nt][2], a2[mt2][nt][3]));
                    }
                }
            }
        }
    }
    if (wave == 2) {
        // finalize coord weights, scatter x
        const int e = lane;
        float4 pv = *(const float4*)&s_cw[e][0];
        float cw = pv.x + pv.y + pv.z + pv.w;
        int sn = s_src[e], dn = s_dst[e];
        float dx0 = x_in[sn * 3 + 0] - x_in[dn * 3 + 0];
        float dx1 = x_in[sn * 3 + 1] - x_in[dn * 3 + 1];
        float dx2 = x_in[sn * 3 + 2] - x_in[dn * 3 + 2];
        atomicAdd(&x_out[dn * 3 + 0], cw * dx0);
        atomicAdd(&x_out[dn * 3 + 1], cw * dx1);
        atomicAdd(&x_out[dn * 3 + 2], cw * dx2);
    }
}

// ======================= node kernel: h += T@Wn2 + deg*bn2 ==================
// R11: 32 nodes/block (was 64) -> 1563 blocks ~ 6/CU, acc 16 AGPR.
// Doubles block-level parallelism for this latency-bound streaming kernel;
// Tbf/Tf32 traffic unchanged (rows read once), wn2 L2 re-reads absorbed.
__global__ __launch_bounds__(256) void node_kernel(
        const unsigned short* __restrict__ Tbf, const float* __restrict__ Tf32,
        const unsigned char* __restrict__ bflag, const int* __restrict__ deg,
        const unsigned short* __restrict__ wn2_l, const float* __restrict__ bn2l,
        float* __restrict__ h, unsigned short* __restrict__ hbf)
{
    const int nb = blockIdx.x * 32;
    const int tid = threadIdx.x;
    const int wave = tid >> 6, lane = tid & 63;
    const int m = lane & 15, q = lane >> 4;

    int fl[2];
    #pragma unroll
    for (int mt = 0; mt < 2; ++mt) {
        const int node = nb + mt * 16 + m;
        fl[mt] = (node < NN) ? (int)bflag[node] : 0;
    }

    f32x4 acc[2][2];   // [nt][mt]
    #pragma unroll
    for (int nt = 0; nt < 2; ++nt)
        #pragma unroll
        for (int mt = 0; mt < 2; ++mt)
            acc[nt][mt] = (f32x4){0.f, 0.f, 0.f, 0.f};

    #pragma unroll
    for (int ks = 0; ks < 8; ++ks) {
        bf16x8 af[2];
        #pragma unroll
        for (int mt = 0; mt < 2; ++mt) {
            const int node = nb + mt * 16 + m;
            if (node < NN) {
                if (!fl[mt]) {
                    af[mt] = *(const bf16x8*)(Tbf + (size_t)node * 256 + ks * 32 + q * 8);
                } else {
                    const float* tp = Tf32 + (size_t)node * 256 + ks * 32 + q * 8;
                    float4 f0 = *(const float4*)tp;
                    float4 f1 = *(const float4*)(tp + 4);
                    unsigned u[4] = { pk_bf16(f0.x, f0.y), pk_bf16(f0.z, f0.w),
                                      pk_bf16(f1.x, f1.y), pk_bf16(f1.z, f1.w) };
                    af[mt] = *(const bf16x8*)u;
                }
            } else {
                af[mt] = (bf16x8){0,0,0,0,0,0,0,0};
            }
        }
        #pragma unroll
        for (int nt = 0; nt < 2; ++nt) {
            bf16x8 wf = *(const bf16x8*)(wn2_l +
                ((size_t)((wave * 2 + nt) * 8 + ks) * 64 + lane) * 8);
            #pragma unroll
            for (int mt = 0; mt < 2; ++mt)
                acc[nt][mt] = __builtin_amdgcn_mfma_f32_16x16x32_bf16(af[mt], wf, acc[nt][mt], 0, 0, 0);
        }
    }
    #pragma unroll
    for (int nt = 0; nt < 2; ++nt) {
        const int col = (wave * 2 + nt) * 16 + m;
        const float bb = bn2l[col];
        #pragma unroll
        for (int mt = 0; mt < 2; ++mt) {
            #pragma unroll
            for (int i = 0; i < 4; ++i) {
                const int node = nb + mt * 16 + q * 4 + i;
                if (node < NN) {
                    float val = acc[nt][mt][i] + (float)deg[node] * bb
                              + h[(size_t)node * CD + col];
                    h[(size_t)node * CD + col] = val;
                    hbf[(size_t)node * CD + col] = f2bf(val);
                }
            }
        }
    }
}

// ======================= final layernorm ====================================
__global__ __launch_bounds__(256) void final_kernel(
        const float* __restrict__ h, const float* __restrict__ x,
        const float* __restrict__ gamma, const float* __restrict__ beta,
        float* __restrict__ out)
{
    const int lane = threadIdx.x & 63;
    const int wave = threadIdx.x >> 6;
    const int n = blockIdx.x * 4 + wave;
    float v0 = h[(size_t)n * CD + lane];
    float v1 = h[(size_t)n * CD + 64 + lane];
    float ssum = v0 + v1;
    for (int off = 32; off; off >>= 1) ssum += __shfl_xor(ssum, off);
    float mu = ssum * (1.f / 128.f);
    float d0 = v0 - mu, d1 = v1 - mu;
    float sq = d0 * d0 + d1 * d1;
    for (int off = 32; off; off >>= 1) sq += __shfl_xor(sq, off);
    float rstd = rsqrtf(sq * (1.f / 128.f) + 1e-5f);
    out[(size_t)n * CD + lane]      = gamma[lane]      * d0 * rstd + beta[lane];
    out[(size_t)n * CD + 64 + lane] = gamma[64 + lane] * d1 * rstd + beta[64 + lane];
    if (threadIdx.x < 12) {
        int nn = blockIdx.x * 4 + threadIdx.x / 3;
        int c = threadIdx.x % 3;
        out[(size_t)NN * CD + nn * 3 + c] = x[nn * 3 + c];
    }
}

static inline size_t align_up(size_t v) { return (v + 255) & ~(size_t)255; }

extern "C" void kernel_launch(void* const* d_in, const int* in_sizes, int n_in,
                              void* d_out, int out_size, void* d_ws, size_t ws_size,
                              hipStream_t stream)
{
    const float* single = (const float*)d_in[0];
    const float* coords = (const float*)d_in[2];
    const int*   eidx   = (const int*)d_in[3];
    const float* edist  = (const float*)d_in[4];
    const float* We1 = (const float*)d_in[5];
    const float* be1 = (const float*)d_in[6];
    const float* We2 = (const float*)d_in[7];
    const float* be2 = (const float*)d_in[8];
    const float* Wn1 = (const float*)d_in[9];
    const float* bn1 = (const float*)d_in[10];
    const float* Wn2 = (const float*)d_in[11];
    const float* bn2 = (const float*)d_in[12];
    const float* Wc1 = (const float*)d_in[13];
    const float* bc1 = (const float*)d_in[14];
    const float* Wc2 = (const float*)d_in[15];
    const float* gamma = (const float*)d_in[16];
    const float* beta  = (const float*)d_in[17];
    float* out = (float*)d_out;

    char* w = (char*)d_ws;
    float* h0  = (float*)w;  w += align_up((size_t)NN * CD * 4);
    float* x0  = (float*)w;  w += align_up((size_t)NN * 3 * 4);
    float* x1  = (float*)w;  w += align_up((size_t)NN * 3 * 4);
    unsigned short* hbf  = (unsigned short*)w; w += align_up((size_t)NN * CD * 2);
    unsigned short* wbig = (unsigned short*)w; w += align_up((size_t)4 * 512 * 320 * 2);
    unsigned short* wn2s = (unsigned short*)w; w += align_up((size_t)4 * 256 * 128 * 2);
    float* cep = (float*)w;  w += align_up((size_t)4 * 512 * 4);
    int* hist   = (int*)w;   w += align_up((size_t)HBINS * 4);
    int* offs   = (int*)w;   w += align_up((size_t)HBINS * 4);
    int* cursor = (int*)w;   w += align_up((size_t)HBINS * 4);
    int* bsum   = (int*)w;   w += align_up((size_t)256 * 4);
    int* ssrc   = (int*)w;   w += align_up((size_t)NE * 4);
    int* sdst   = (int*)w;   w += align_up((size_t)NE * 4);
    float* sdist = (float*)w; w += align_up((size_t)NE * 4);
    unsigned char* bflag = (unsigned char*)w; w += align_up((size_t)NN);
    unsigned short* Tbf = (unsigned short*)w; w += align_up((size_t)NN * 256 * 2);
    float* Tf32 = (float*)w; w += align_up((size_t)NN * 256 * 4);

    // ---- sort edges by dst (once; constant across layers) ----
    hipMemsetAsync(hist, 0, (size_t)HBINS * 4, stream);
    hist_kernel<<<(NE + 255) / 256, 256, 0, stream>>>(eidx + NE, hist);
    scan1_kernel<<<HBINS / 256, 256, 0, stream>>>(hist, offs, bsum);
    scan2_kernel<<<1, 256, 0, stream>>>(bsum);
    scan3_kernel<<<HBINS / 256, 256, 0, stream>>>(offs, bsum, cursor);
    scatter_kernel<<<(NE + 255) / 256, 256, 0, stream>>>(eidx, edist, cursor, ssrc, sdst, sdist);
    hipMemsetAsync(bflag, 0, (size_t)NN, stream);
    bflag_kernel<<<(NBLK + 255) / 256, 256, 0, stream>>>(sdst, bflag);

    // ---- weight prep ----
    wbig_prep<<<dim3(320, 4), 64, 0, stream>>>(We2, Wn1, Wc1, wbig);
    wn2_prep<<<dim3(64, 4), 64, 0, stream>>>(Wn2, wn2s);
    cep_prep<<<4, 512, 0, stream>>>(be2, Wn1, Wc1, bn1, bc1, cep);

    hipMemcpyAsync(h0, single, (size_t)NN * CD * 4, hipMemcpyDeviceToDevice, stream);
    hipMemcpyAsync(x0, coords, (size_t)NN * 3 * 4, hipMemcpyDeviceToDevice, stream);
    conv_kernel<<<(NN * CD) / 1024, 256, 0, stream>>>(single, hbf);

    // Tbf zeroed ONCE (verified R9/R10-correct): interior rows fully
    // rewritten every layer, boundary rows read from Tf32 (bflag),
    // deg-0 rows stay zero.
    hipMemsetAsync(Tbf, 0, (size_t)NN * 256 * 2, stream);

    float* xc = x0; float* xn = x1;
    for (int l = 0; l < 4; ++l) {
        zside_kernel<<<NBLK, 128, 0, stream>>>(sdst, Tf32);     // boundary rows
        hipMemcpyAsync(xn, xc, (size_t)NN * 3 * 4, hipMemcpyDeviceToDevice, stream);
        edge_kernel<<<NBLK, 512, 0, stream>>>(
            ssrc, sdst, sdist,
            We1 + l * 64, be1 + l * 64,
            hbf,
            wbig + (size_t)l * 512 * 320,
            cep + l * 512,
            Wc2 + l * 256,
            xc, Tbf, Tf32, xn);
        node_kernel<<<(NN + 31) / 32, 256, 0, stream>>>(
            Tbf, Tf32, bflag, hist,
            wn2s + (size_t)l * 256 * 128,
            bn2 + l * CD, h0, hbf);
        float* t = xc; xc = xn; xn = t;
    }
    final_kernel<<<NN / 4, 256, 0, stream>>>(h0, xc, gamma, beta, out);
}